// Round 9
// baseline (2413.997 us; speedup 1.0000x reference)
//
#include <hip/hip_runtime.h>
#include <hip/hip_bf16.h>
#include <hip/hip_fp8.h>
#include <stdint.h>
#include <stddef.h>

#define NW    4096
#define LSEQ  24
#define HDIM  512
#define DWG   300
#define DCC   128
#define VCC   100
#define G4H   2048
#define CATD  812
#define HIDD  512
#define NOUT  5
#define NBLK  128   // LSTM blocks (32 rows each, no cross-block deps)

typedef float f32x16 __attribute__((ext_vector_type(16)));

__device__ __forceinline__ float frcp(float x) { return __builtin_amdgcn_rcpf(x); }
__device__ __forceinline__ float sigf(float x) { return frcp(1.0f + __expf(-x)); }
__device__ __forceinline__ float tanh_fast(float x) { return fmaf(2.0f, frcp(1.0f + __expf(-2.0f * x)), -1.0f); }

// ---- retile W_hh f32 [2048][512] -> fp8 e4m3 (x8 scale) in EXACT per-wave read order ----
// wt layout: [chunk o=(a,kp) 64][wave w 8][frag f=(p,gg) 4][lane 64] x 8 fp8 (chunk=16KB).
// content[o][w][f][lane][i] = fp8(8 * W_hh[(a+2*gg)*512 + (w*2+p)*32 + l31][kp*16 + lhi*8 + i])
__global__ void k_convert_wtile8(const float* __restrict__ whh, unsigned char* __restrict__ wt) {
    const int tid = blockIdx.x * 256 + threadIdx.x;   // 131072
    const int lane = tid & 63, f = (tid >> 6) & 3, w = (tid >> 8) & 7, o = tid >> 11;
    const int a = o >> 5, kp = o & 31;
    const int p = f >> 1, gg = f & 1;
    const int l31 = lane & 31, lhi = lane >> 5;
    const int j = (a + 2 * gg) * 512 + (w * 2 + p) * 32 + l31;
    const int k = kp * 16 + lhi * 8;
    const float* src = whh + (size_t)j * HDIM + k;
    union { unsigned char b[8]; long v; } u;
#pragma unroll
    for (int i = 0; i < 8; ++i) u.b[i] = __hip_fp8_e4m3(src[i] * 8.0f).__x;
    *reinterpret_cast<long*>(wt + (size_t)tid * 8) = u.v;
}

// ---- char_proj[c][j] = char_embed[c,:] @ W_ih[j,:] + b_ih[j] + b_hh[j]  (bf16 out) ----
__global__ void k_char_proj(const float* __restrict__ cemb, const float* __restrict__ wih,
                            const float* __restrict__ bih, const float* __restrict__ bhh,
                            __hip_bfloat16* __restrict__ cproj) {
    __shared__ float emb[DCC];
    const int c = blockIdx.x;
    if (threadIdx.x < DCC) emb[threadIdx.x] = cemb[c * DCC + threadIdx.x];
    __syncthreads();
    for (int j = threadIdx.x; j < G4H; j += blockDim.x) {
        const float* w = wih + (size_t)j * DCC;
        float acc = bih[j] + bhh[j];
#pragma unroll 4
        for (int k = 0; k < DCC; ++k) acc = fmaf(emb[k], w[k], acc);
        cproj[(size_t)c * G4H + j] = __float2bfloat16(acc);
    }
}

#define RIN(q) (((q) & 3) + (((q) >> 2) << 3) + (lhi << 2))
#define LENQ(q) ((lp[(q) >> 2] >> (((q) & 3) * 8)) & 0xff)

// consume one chunk slot (4 frags) + refill it from chunk RC
#define CRF(P0, P1, P2, P3, KPV, RC)                                              \
    {                                                                             \
        const long av = *reinterpret_cast<const long*>(                           \
            hb + (l31 << 9) + ((((KPV) << 4) | (lhi << 3)) ^ xr8));               \
        ac0 = __builtin_amdgcn_mfma_f32_32x32x16_fp8_fp8(av, P0, ac0, 0, 0, 0);   \
        ac1 = __builtin_amdgcn_mfma_f32_32x32x16_fp8_fp8(av, P1, ac1, 0, 0, 0);   \
        ac2 = __builtin_amdgcn_mfma_f32_32x32x16_fp8_fp8(av, P2, ac2, 0, 0, 0);   \
        ac3 = __builtin_amdgcn_mfma_f32_32x32x16_fp8_fp8(av, P3, ac3, 0, 0, 0);   \
        const char* nc = wbase + (size_t)((RC) & 63) * 16384;                     \
        P0 = *reinterpret_cast<const long*>(nc);                                  \
        P1 = *reinterpret_cast<const long*>(nc + 512);                            \
        P2 = *reinterpret_cast<const long*>(nc + 1024);                           \
        P3 = *reinterpret_cast<const long*>(nc + 1536);                           \
    }

// ---- LSTM: 128 blocks x 512 thr (8 waves, 2/SIMD). h in swizzled 16KB fp8 LDS (x8 scale).
// W fp8 (x8) streamed L2->VGPR, continuous 4-deep named-register pipeline across passes
// AND steps (pass-A tail prefetches pass-B chunks; pass-B tail prefetches next step).
// Gates: pass A = i,g (chunks 0..31); pass B = f,o (chunks 32..63). acc scale 1/64.
__global__ void __launch_bounds__(512, 2) k_lstm_block(
        const unsigned char* __restrict__ wt,      // retiled fp8 W (see k_convert_wtile8)
        const __hip_bfloat16* __restrict__ cproj,  // [100][2048] bf16
        const int* __restrict__ cidx,              // [NW][LSEQ]
        const int* __restrict__ clen,              // [NW]
        float* __restrict__ pchar) {               // [NBLK][512] partial col sums
    __shared__ long hb8[2048];                     // 16 KB h (fp8, x8, swizzled)
    char* hb = (char*)hb8;
    const int b = blockIdx.x;
    const int tid = threadIdx.x;
    const int w = tid >> 6, lane = tid & 63;
    const int l31 = lane & 31, lhi = lane >> 5;
    const int n0 = b * 32;
    const int xr8 = (l31 & 15) << 3;
    const float S = 0.015625f;                     // 1/64 (W x8, h x8)

    const char* wbase = (const char*)wt + w * 2048 + lane * 8;   // + chunk*16384 + f*512

    int lp[4];
#pragma unroll
    for (int j = 0; j < 4; ++j) {
        int v = 0;
#pragma unroll
        for (int k = 0; k < 4; ++k) v |= (clen[n0 + j * 8 + (lhi << 2) + k] & 0xff) << (k * 8);
        lp[j] = v;
    }

    float cs[2][16];
#pragma unroll
    for (int p = 0; p < 2; ++p)
#pragma unroll
        for (int q = 0; q < 16; ++q) cs[p][q] = 0.0f;

    // prologue: fill 4 slots with chunks 0..3 (latency hides under t=0 epilogue)
    long A0, A1, A2, A3, B0, B1, B2, B3, C0, C1, C2, C3, D0, D1, D2, D3;
    {
        const char* nc = wbase;
        A0 = *reinterpret_cast<const long*>(nc);
        A1 = *reinterpret_cast<const long*>(nc + 512);
        A2 = *reinterpret_cast<const long*>(nc + 1024);
        A3 = *reinterpret_cast<const long*>(nc + 1536);
        nc += 16384;
        B0 = *reinterpret_cast<const long*>(nc);
        B1 = *reinterpret_cast<const long*>(nc + 512);
        B2 = *reinterpret_cast<const long*>(nc + 1024);
        B3 = *reinterpret_cast<const long*>(nc + 1536);
        nc += 16384;
        C0 = *reinterpret_cast<const long*>(nc);
        C1 = *reinterpret_cast<const long*>(nc + 512);
        C2 = *reinterpret_cast<const long*>(nc + 1024);
        C3 = *reinterpret_cast<const long*>(nc + 1536);
        nc += 16384;
        D0 = *reinterpret_cast<const long*>(nc);
        D1 = *reinterpret_cast<const long*>(nc + 512);
        D2 = *reinterpret_cast<const long*>(nc + 1024);
        D3 = *reinterpret_cast<const long*>(nc + 1536);
    }

    int ci16[16];
#pragma unroll
    for (int q = 0; q < 16; ++q) ci16[q] = cidx[(n0 + RIN(q)) * LSEQ];

    // ---- t = 0: h,c = 0 -> gates from cproj only; write full h1 (fp8, x8) ----
#pragma unroll
    for (int p = 0; p < 2; ++p) {
        const int colh = ((w << 1) + p) * 32 + l31;
#pragma unroll
        for (int q = 0; q < 16; ++q) {
            float hv = 0.0f;
            if (0 < LENQ(q)) {
                const __hip_bfloat16* cp = cproj + ((size_t)ci16[q] << 11) + colh;
                const float i_s = sigf(__bfloat162float(cp[0]));
                const float g_t = tanh_fast(__bfloat162float(cp[1024]));
                const float o_s = sigf(__bfloat162float(cp[1536]));
                const float cn = i_s * g_t;
                cs[p][q] = cn;
                hv = o_s * tanh_fast(cn);
            }
            hb[(RIN(q) << 9) + (colh ^ ((RIN(q) & 15) << 3))] =
                __hip_fp8_e4m3(hv * 8.0f).__x;
        }
    }
    __syncthreads();

    for (int t = 1; t < LSEQ; ++t) {
#pragma unroll
        for (int q = 0; q < 16; ++q) ci16[q] = cidx[(n0 + RIN(q)) * LSEQ + t];

        float ig[2][16];

        // ===== pass A: gates i, g (chunks 0..31); tail prefetches chunks 32..35 =====
        {
            f32x16 ac0 = {}, ac1 = {}, ac2 = {}, ac3 = {};
#pragma unroll
            for (int k4 = 0; k4 < 8; ++k4) {
                const int kp = k4 * 4;
                CRF(A0, A1, A2, A3, kp + 0, kp + 4)
                CRF(B0, B1, B2, B3, kp + 1, kp + 5)
                CRF(C0, C1, C2, C3, kp + 2, kp + 6)
                CRF(D0, D1, D2, D3, kp + 3, kp + 7)
            }
#pragma unroll
            for (int p = 0; p < 2; ++p) {
                const int colh = ((w << 1) + p) * 32 + l31;
                const f32x16& ai = p ? ac2 : ac0;
                const f32x16& ag = p ? ac3 : ac1;
#pragma unroll
                for (int q = 0; q < 16; ++q) {
                    float v = 0.0f;
                    if (t < LENQ(q)) {
                        const __hip_bfloat16* cp = cproj + ((size_t)ci16[q] << 11) + colh;
                        v = sigf(fmaf(ai[q], S, __bfloat162float(cp[0]))) *
                            tanh_fast(fmaf(ag[q], S, __bfloat162float(cp[1024])));
                    }
                    ig[p][q] = v;
                }
            }
        }

        // ===== pass B: gates f, o (chunks 32..63); tail prefetches next step's 0..3 =====
        {
            f32x16 ac0 = {}, ac1 = {}, ac2 = {}, ac3 = {};
#pragma unroll
            for (int k4 = 0; k4 < 8; ++k4) {
                const int kp = k4 * 4;
                CRF(A0, A1, A2, A3, kp + 0, 32 + kp + 4)
                CRF(B0, B1, B2, B3, kp + 1, 32 + kp + 5)
                CRF(C0, C1, C2, C3, kp + 2, 32 + kp + 6)
                CRF(D0, D1, D2, D3, kp + 3, 32 + kp + 7)
            }
            __syncthreads();   // all waves done reading h_t
#pragma unroll
            for (int p = 0; p < 2; ++p) {
                const int colh = ((w << 1) + p) * 32 + l31;
                const f32x16& af = p ? ac2 : ac0;
                const f32x16& ao = p ? ac3 : ac1;
#pragma unroll
                for (int q = 0; q < 16; ++q) {
                    if (t < LENQ(q)) {
                        const __hip_bfloat16* cp = cproj + ((size_t)ci16[q] << 11) + colh;
                        const float f_s = sigf(fmaf(af[q], S, __bfloat162float(cp[512])));
                        const float o_s = sigf(fmaf(ao[q], S, __bfloat162float(cp[1536])));
                        const float cn = fmaf(f_s, cs[p][q], ig[p][q]);
                        cs[p][q] = cn;
                        hb[(RIN(q) << 9) + (colh ^ ((RIN(q) & 15) << 3))] =
                            __hip_fp8_e4m3(o_s * tanh_fast(cn) * 8.0f).__x;
                    }   // frozen rows keep old value (single buffer)
                }
            }
            __syncthreads();   // h_{t+1} visible
        }
    }

    // block-local masked column partial sums (values are h*8 -> scale by 1/8)
#pragma unroll
    for (int p = 0; p < 2; ++p) {
        const int colh = ((w << 1) + p) * 32 + l31;
        float s = 0.0f;
#pragma unroll
        for (int q = 0; q < 16; ++q) {
            if (LENQ(q) >= 2) {
                __hip_fp8_e4m3 v;
                v.__x = (unsigned char)hb[(RIN(q) << 9) + (colh ^ ((RIN(q) & 15) << 3))];
                s += (float)v;
            }
        }
        s *= 0.125f;
        s += __shfl_xor(s, 32, 64);
        if (lhi == 0) pchar[b * HDIM + colh] = s;
    }
}

// ---- glove gather column sums, 5x16 partial grid ----
__global__ void k_sum_glove(const float* __restrict__ gt, const int* __restrict__ widx,
                            float* __restrict__ pglove) {
    const int col = blockIdx.x * 64 + (threadIdx.x & 63);
    const int phase = threadIdx.x >> 6;
    const int nbase = blockIdx.y * 256;
    float s = 0.0f;
    if (col < DWG) {
        for (int n = nbase + phase; n < nbase + 256; n += 4) {
            s += gt[(size_t)widx[n] * DWG + col];
        }
    }
    __shared__ float red[256];
    red[threadIdx.x] = s;
    __syncthreads();
    if (phase == 0 && col < DWG) {
        pglove[blockIdx.y * DWG + col] =
            red[threadIdx.x] + red[threadIdx.x + 64] + red[threadIdx.x + 128] + red[threadIdx.x + 192];
    }
}

// ---- combine partials -> avg vector ----
__global__ void k_avg(const float* __restrict__ pglove, const float* __restrict__ pchar,
                      float* __restrict__ avg) {
    const int i = blockIdx.x * 256 + threadIdx.x;
    if (i >= CATD) return;
    float s = 0.0f;
    if (i < DWG) {
        for (int r = 0; r < 16; ++r) s += pglove[r * DWG + i];
    } else {
        const int c = i - DWG;
        for (int r = 0; r < NBLK; ++r) s += pchar[r * HDIM + c];
    }
    avg[i] = s * (1.0f / 4096.0f);
}

__global__ void k_fc1(const float* __restrict__ avg, const float* __restrict__ W,
                      const float* __restrict__ bias, float* __restrict__ h1) {
    const int wave = threadIdx.x >> 6, lane = threadIdx.x & 63;
    const int j = blockIdx.x * 8 + wave;
    const float* w = W + (size_t)j * CATD;
    float s = 0.0f;
    for (int k = lane; k < CATD; k += 64) s += avg[k] * w[k];
#pragma unroll
    for (int o = 32; o > 0; o >>= 1) s += __shfl_down(s, o, 64);
    if (lane == 0) h1[j] = sigf(s + bias[j]);
}

__global__ void k_fc2(const float* __restrict__ h1, const float* __restrict__ W,
                      const float* __restrict__ bias, float* __restrict__ out) {
    const int wave = threadIdx.x >> 6, lane = threadIdx.x & 63;
    const float* w = W + (size_t)wave * HIDD;
    float s = 0.0f;
    for (int k = lane; k < HIDD; k += 64) s += h1[k] * w[k];
#pragma unroll
    for (int o = 32; o > 0; o >>= 1) s += __shfl_down(s, o, 64);
    if (lane == 0) out[wave] = s + bias[wave];
}

extern "C" void kernel_launch(void* const* d_in, const int* in_sizes, int n_in,
                              void* d_out, int out_size, void* d_ws, size_t ws_size,
                              hipStream_t stream) {
    (void)in_sizes; (void)n_in; (void)out_size; (void)ws_size;
    const int*   widx  = (const int*)d_in[0];
    const int*   cidx  = (const int*)d_in[1];
    const int*   clen  = (const int*)d_in[2];
    const float* glove = (const float*)d_in[3];
    const float* cemb  = (const float*)d_in[4];
    const float* wih   = (const float*)d_in[5];
    const float* whh   = (const float*)d_in[6];
    const float* bih   = (const float*)d_in[7];
    const float* bhh   = (const float*)d_in[8];
    const float* fc1W  = (const float*)d_in[9];
    const float* fc1b  = (const float*)d_in[10];
    const float* fc2W  = (const float*)d_in[11];
    const float* fc2b  = (const float*)d_in[12];
    float* out = (float*)d_out;

    char* ws = (char*)d_ws;
    unsigned char*  wt8    = (unsigned char*)(ws);                      // 1 MB
    __hip_bfloat16* cproj  = (__hip_bfloat16*)(ws + (1u << 20));        // 400 KB
    float*          pchar  = (float*)(ws + (1536u << 10));              // 256 KB
    float*          pglove = (float*)(ws + (1792u << 10));              // 19.2 KB
    float*          avg    = (float*)(ws + (1824u << 10));              // 3.2 KB
    float*          h1g    = (float*)(ws + (1832u << 10));              // 2 KB

    k_convert_wtile8<<<512, 256, 0, stream>>>(whh, wt8);
    k_char_proj<<<VCC, 256, 0, stream>>>(cemb, wih, bih, bhh, cproj);
    k_lstm_block<<<NBLK, 512, 0, stream>>>(wt8, cproj, cidx, clen, pchar);
    k_sum_glove<<<dim3(5, 16), 256, 0, stream>>>(glove, widx, pglove);
    k_avg<<<4, 256, 0, stream>>>(pglove, pchar, avg);
    k_fc1<<<64, 512, 0, stream>>>(avg, fc1W, fc1b, h1g);
    k_fc2<<<1, 320, 0, stream>>>(h1g, fc2W, fc2b, out);
}

// Round 10
// 2147.843 us; speedup vs baseline: 1.1239x; 1.1239x over previous
//
#include <hip/hip_runtime.h>
#include <hip/hip_bf16.h>
#include <hip/hip_fp8.h>
#include <stdint.h>
#include <stddef.h>

#define NW    4096
#define LSEQ  24
#define HDIM  512
#define DWG   300
#define DCC   128
#define VCC   100
#define G4H   2048
#define CATD  812
#define HIDD  512
#define NOUT  5
#define NBLK  128   // LSTM blocks (32 rows each, no cross-block deps)

typedef float f32x16 __attribute__((ext_vector_type(16)));

__device__ __forceinline__ float frcp(float x) { return __builtin_amdgcn_rcpf(x); }
__device__ __forceinline__ float sigf(float x) { return frcp(1.0f + __expf(-x)); }
__device__ __forceinline__ float tanh_fast(float x) { return fmaf(2.0f, frcp(1.0f + __expf(-2.0f * x)), -1.0f); }

// ---- retile W_hh f32 [2048][512] -> fp8 e4m3 (x8) in EXACT per-wave read order ----
// wt layout: [chunk o=(p,kp) 64][wave w 8][gate f 4][lane 64] x 8 fp8 (chunk = 16 KB).
// content = fp8(8 * W_hh[f*512 + (w*2+p)*32 + l31][kp*16 + lhi*8 + i])
__global__ void k_convert_wtile8(const float* __restrict__ whh, unsigned char* __restrict__ wt) {
    const int tid = blockIdx.x * 256 + threadIdx.x;   // 131072
    const int lane = tid & 63, f = (tid >> 6) & 3, w = (tid >> 8) & 7, o = tid >> 11;
    const int p = o >> 5, kp = o & 31;
    const int l31 = lane & 31, lhi = lane >> 5;
    const int j = f * 512 + (w * 2 + p) * 32 + l31;
    const int k = kp * 16 + lhi * 8;
    const float* src = whh + (size_t)j * HDIM + k;
    union { unsigned char b[8]; long v; } u;
#pragma unroll
    for (int i = 0; i < 8; ++i) u.b[i] = __hip_fp8_e4m3(src[i] * 8.0f).__x;
    *reinterpret_cast<long*>(wt + (size_t)tid * 8) = u.v;
}

// ---- char_proj[c][j] = char_embed[c,:] @ W_ih[j,:] + b_ih[j] + b_hh[j]  (bf16 out) ----
__global__ void k_char_proj(const float* __restrict__ cemb, const float* __restrict__ wih,
                            const float* __restrict__ bih, const float* __restrict__ bhh,
                            __hip_bfloat16* __restrict__ cproj) {
    __shared__ float emb[DCC];
    const int c = blockIdx.x;
    if (threadIdx.x < DCC) emb[threadIdx.x] = cemb[c * DCC + threadIdx.x];
    __syncthreads();
    for (int j = threadIdx.x; j < G4H; j += blockDim.x) {
        const float* w = wih + (size_t)j * DCC;
        float acc = bih[j] + bhh[j];
#pragma unroll 4
        for (int k = 0; k < DCC; ++k) acc = fmaf(emb[k], w[k], acc);
        cproj[(size_t)c * G4H + j] = __float2bfloat16(acc);
    }
}

#define RIN(q) (((q) & 3) + (((q) >> 2) << 3) + (lhi << 2))
#define LENQ(q) ((lp[(q) >> 2] >> (((q) & 3) * 8)) & 0xff)

// consume one chunk slot (4 gate frags) + refill it from absolute chunk RC
#define CRF(P0, P1, P2, P3, KPV, RC)                                              \
    {                                                                             \
        const long av = *reinterpret_cast<const long*>(                           \
            hrd + (l31 << 9) + ((((KPV) << 4) | (lhi << 3)) ^ xr8));              \
        ac0 = __builtin_amdgcn_mfma_f32_32x32x16_fp8_fp8(av, P0, ac0, 0, 0, 0);   \
        ac1 = __builtin_amdgcn_mfma_f32_32x32x16_fp8_fp8(av, P1, ac1, 0, 0, 0);   \
        ac2 = __builtin_amdgcn_mfma_f32_32x32x16_fp8_fp8(av, P2, ac2, 0, 0, 0);   \
        ac3 = __builtin_amdgcn_mfma_f32_32x32x16_fp8_fp8(av, P3, ac3, 0, 0, 0);   \
        const char* nc = wbase + (size_t)((RC) & 63) * 16384;                     \
        P0 = *reinterpret_cast<const long*>(nc);                                  \
        P1 = *reinterpret_cast<const long*>(nc + 512);                            \
        P2 = *reinterpret_cast<const long*>(nc + 1024);                           \
        P3 = *reinterpret_cast<const long*>(nc + 1536);                           \
    }

#define GRP16(CB, K0)                                   \
    CRF(A0, A1, A2, A3, (K0) + 0, (CB) + (K0) + 4)      \
    CRF(B0, B1, B2, B3, (K0) + 1, (CB) + (K0) + 5)      \
    CRF(C0, C1, C2, C3, (K0) + 2, (CB) + (K0) + 6)      \
    CRF(D0, D1, D2, D3, (K0) + 3, (CB) + (K0) + 7)

#define KLOOP(CB)                                               \
    GRP16(CB, 0)  GRP16(CB, 4)  GRP16(CB, 8)  GRP16(CB, 12)     \
    GRP16(CB, 16) GRP16(CB, 20) GRP16(CB, 24) GRP16(CB, 28)

// one pass: all 4 gates for column half PP; full LSTM update in epilogue (no ig carry)
#define PASS(CB, PP, CS)                                                           \
    {                                                                              \
        f32x16 ac0 = {}, ac1 = {}, ac2 = {}, ac3 = {};                             \
        KLOOP(CB)                                                                  \
        const int colh = ((w << 1) + (PP)) * 32 + l31;                             \
        _Pragma("unroll")                                                          \
        for (int q = 0; q < 16; ++q) {                                             \
            const int rin = RIN(q);                                                \
            const int sw = (rin << 9) + (colh ^ ((rin & 15) << 3));                \
            if (t < LENQ(q)) {                                                     \
                const __hip_bfloat16* cp = cproj + ((size_t)ci16[q] << 11) + colh; \
                const float gi = fmaf(ac0[q], S, __bfloat162float(cp[0]));         \
                const float gf = fmaf(ac1[q], S, __bfloat162float(cp[512]));       \
                const float gg = fmaf(ac2[q], S, __bfloat162float(cp[1024]));      \
                const float go = fmaf(ac3[q], S, __bfloat162float(cp[1536]));      \
                const float cn = fmaf(sigf(gf), CS[q], sigf(gi) * tanh_fast(gg));  \
                CS[q] = cn;                                                        \
                hwr[sw] = __hip_fp8_e4m3(sigf(go) * tanh_fast(cn) * 8.0f).__x;     \
            } else {                                                               \
                hwr[sw] = hrd[sw];                                                 \
            }                                                                      \
        }                                                                          \
    }

// ---- LSTM: 128 blocks x 512 thr (8 waves, 2/SIMD; arch-VGPR demand ~110 < 128 cap).
// h fp8 (x8) in 2x16KB swizzled LDS dbuf; W fp8 (x8) streamed L2->VGPR with continuous
// 4-deep named-register pipeline across passes AND steps. Pass = column half (all 4
// gates). ONE __syncthreads per step. Gate acc scale 1/64.
__global__ void __launch_bounds__(512, 2) k_lstm_block(
        const unsigned char* __restrict__ wt,      // retiled fp8 W
        const __hip_bfloat16* __restrict__ cproj,  // [100][2048] bf16
        const int* __restrict__ cidx,              // [NW][LSEQ]
        const int* __restrict__ clen,              // [NW]
        float* __restrict__ pchar) {               // [NBLK][512] partial col sums
    __shared__ long hbuf[4096];                    // 2 x 16 KB h (fp8, x8, swizzled)
    char* hb = (char*)hbuf;
    const int b = blockIdx.x;
    const int tid = threadIdx.x;
    const int w = tid >> 6, lane = tid & 63;
    const int l31 = lane & 31, lhi = lane >> 5;
    const int n0 = b * 32;
    const int xr8 = (l31 & 15) << 3;
    const float S = 0.015625f;                     // 1/64 (W x8, h x8)

    const char* wbase = (const char*)wt + w * 2048 + lane * 8;   // + chunk*16384 + f*512

    int lp[4];
#pragma unroll
    for (int j = 0; j < 4; ++j) {
        int v = 0;
#pragma unroll
        for (int k = 0; k < 4; ++k) v |= (clen[n0 + j * 8 + (lhi << 2) + k] & 0xff) << (k * 8);
        lp[j] = v;
    }

    float cs0[16], cs1[16];
#pragma unroll
    for (int q = 0; q < 16; ++q) { cs0[q] = 0.0f; cs1[q] = 0.0f; }

    // prologue: fill 4 slots with chunks 0..3 (latency hides under t=0 epilogue)
    long A0, A1, A2, A3, B0, B1, B2, B3, C0, C1, C2, C3, D0, D1, D2, D3;
    {
        const char* nc = wbase;
        A0 = *reinterpret_cast<const long*>(nc);
        A1 = *reinterpret_cast<const long*>(nc + 512);
        A2 = *reinterpret_cast<const long*>(nc + 1024);
        A3 = *reinterpret_cast<const long*>(nc + 1536);
        nc += 16384;
        B0 = *reinterpret_cast<const long*>(nc);
        B1 = *reinterpret_cast<const long*>(nc + 512);
        B2 = *reinterpret_cast<const long*>(nc + 1024);
        B3 = *reinterpret_cast<const long*>(nc + 1536);
        nc += 16384;
        C0 = *reinterpret_cast<const long*>(nc);
        C1 = *reinterpret_cast<const long*>(nc + 512);
        C2 = *reinterpret_cast<const long*>(nc + 1024);
        C3 = *reinterpret_cast<const long*>(nc + 1536);
        nc += 16384;
        D0 = *reinterpret_cast<const long*>(nc);
        D1 = *reinterpret_cast<const long*>(nc + 512);
        D2 = *reinterpret_cast<const long*>(nc + 1024);
        D3 = *reinterpret_cast<const long*>(nc + 1536);
    }

    int ci16[16];
#pragma unroll
    for (int q = 0; q < 16; ++q) ci16[q] = cidx[(n0 + RIN(q)) * LSEQ];

    // ---- t = 0: h,c = 0 -> gates from cproj only; write h1 into buf 1 ----
    {
        char* hwr = hb + 16384;
#pragma unroll
        for (int p = 0; p < 2; ++p) {
            const int colh = ((w << 1) + p) * 32 + l31;
#pragma unroll
            for (int q = 0; q < 16; ++q) {
                const int rin = RIN(q);
                float hv = 0.0f;
                if (0 < LENQ(q)) {
                    const __hip_bfloat16* cp = cproj + ((size_t)ci16[q] << 11) + colh;
                    const float i_s = sigf(__bfloat162float(cp[0]));
                    const float g_t = tanh_fast(__bfloat162float(cp[1024]));
                    const float o_s = sigf(__bfloat162float(cp[1536]));
                    const float cn = i_s * g_t;
                    if (p == 0) cs0[q] = cn; else cs1[q] = cn;
                    hv = o_s * tanh_fast(cn);
                }
                hwr[(rin << 9) + (colh ^ ((rin & 15) << 3))] = __hip_fp8_e4m3(hv * 8.0f).__x;
            }
        }
    }
    __syncthreads();

    for (int t = 1; t < LSEQ; ++t) {
#pragma unroll
        for (int q = 0; q < 16; ++q) ci16[q] = cidx[(n0 + RIN(q)) * LSEQ + t];

        const char* hrd = hb + ((t & 1) << 14);          // h_t
        char*       hwr = hb + (((t + 1) & 1) << 14);    // h_{t+1}

        PASS(0, 0, cs0)    // cols [64w, 64w+32), chunks 0..31, refills 4..35
        PASS(32, 1, cs1)   // cols [64w+32, 64w+64), chunks 32..63, refills 36..63,0..3

        __syncthreads();   // h_{t+1} fully written; next step may read it
    }

    // final h (h_24) is in buf 0; each thread reads only cells it wrote
#pragma unroll
    for (int p = 0; p < 2; ++p) {
        const int colh = ((w << 1) + p) * 32 + l31;
        float s = 0.0f;
#pragma unroll
        for (int q = 0; q < 16; ++q) {
            if (LENQ(q) >= 2) {
                const int rin = RIN(q);
                __hip_fp8_e4m3 v;
                v.__x = (unsigned char)hb[(rin << 9) + (colh ^ ((rin & 15) << 3))];
                s += (float)v;
            }
        }
        s *= 0.125f;
        s += __shfl_xor(s, 32, 64);
        if (lhi == 0) pchar[b * HDIM + colh] = s;
    }
}

// ---- glove gather column sums, 5x16 partial grid ----
__global__ void k_sum_glove(const float* __restrict__ gt, const int* __restrict__ widx,
                            float* __restrict__ pglove) {
    const int col = blockIdx.x * 64 + (threadIdx.x & 63);
    const int phase = threadIdx.x >> 6;
    const int nbase = blockIdx.y * 256;
    float s = 0.0f;
    if (col < DWG) {
        for (int n = nbase + phase; n < nbase + 256; n += 4) {
            s += gt[(size_t)widx[n] * DWG + col];
        }
    }
    __shared__ float red[256];
    red[threadIdx.x] = s;
    __syncthreads();
    if (phase == 0 && col < DWG) {
        pglove[blockIdx.y * DWG + col] =
            red[threadIdx.x] + red[threadIdx.x + 64] + red[threadIdx.x + 128] + red[threadIdx.x + 192];
    }
}

// ---- combine partials -> avg vector ----
__global__ void k_avg(const float* __restrict__ pglove, const float* __restrict__ pchar,
                      float* __restrict__ avg) {
    const int i = blockIdx.x * 256 + threadIdx.x;
    if (i >= CATD) return;
    float s = 0.0f;
    if (i < DWG) {
        for (int r = 0; r < 16; ++r) s += pglove[r * DWG + i];
    } else {
        const int c = i - DWG;
        for (int r = 0; r < NBLK; ++r) s += pchar[r * HDIM + c];
    }
    avg[i] = s * (1.0f / 4096.0f);
}

__global__ void k_fc1(const float* __restrict__ avg, const float* __restrict__ W,
                      const float* __restrict__ bias, float* __restrict__ h1) {
    const int wave = threadIdx.x >> 6, lane = threadIdx.x & 63;
    const int j = blockIdx.x * 8 + wave;
    const float* w = W + (size_t)j * CATD;
    float s = 0.0f;
    for (int k = lane; k < CATD; k += 64) s += avg[k] * w[k];
#pragma unroll
    for (int o = 32; o > 0; o >>= 1) s += __shfl_down(s, o, 64);
    if (lane == 0) h1[j] = sigf(s + bias[j]);
}

__global__ void k_fc2(const float* __restrict__ h1, const float* __restrict__ W,
                      const float* __restrict__ bias, float* __restrict__ out) {
    const int wave = threadIdx.x >> 6, lane = threadIdx.x & 63;
    const float* w = W + (size_t)wave * HIDD;
    float s = 0.0f;
    for (int k = lane; k < HIDD; k += 64) s += h1[k] * w[k];
#pragma unroll
    for (int o = 32; o > 0; o >>= 1) s += __shfl_down(s, o, 64);
    if (lane == 0) out[wave] = s + bias[wave];
}

extern "C" void kernel_launch(void* const* d_in, const int* in_sizes, int n_in,
                              void* d_out, int out_size, void* d_ws, size_t ws_size,
                              hipStream_t stream) {
    (void)in_sizes; (void)n_in; (void)out_size; (void)ws_size;
    const int*   widx  = (const int*)d_in[0];
    const int*   cidx  = (const int*)d_in[1];
    const int*   clen  = (const int*)d_in[2];
    const float* glove = (const float*)d_in[3];
    const float* cemb  = (const float*)d_in[4];
    const float* wih   = (const float*)d_in[5];
    const float* whh   = (const float*)d_in[6];
    const float* bih   = (const float*)d_in[7];
    const float* bhh   = (const float*)d_in[8];
    const float* fc1W  = (const float*)d_in[9];
    const float* fc1b  = (const float*)d_in[10];
    const float* fc2W  = (const float*)d_in[11];
    const float* fc2b  = (const float*)d_in[12];
    float* out = (float*)d_out;

    char* ws = (char*)d_ws;
    unsigned char*  wt8    = (unsigned char*)(ws);                      // 1 MB
    __hip_bfloat16* cproj  = (__hip_bfloat16*)(ws + (1u << 20));        // 400 KB
    float*          pchar  = (float*)(ws + (1536u << 10));              // 256 KB
    float*          pglove = (float*)(ws + (1792u << 10));              // 19.2 KB
    float*          avg    = (float*)(ws + (1824u << 10));              // 3.2 KB
    float*          h1g    = (float*)(ws + (1832u << 10));              // 2 KB

    k_convert_wtile8<<<512, 256, 0, stream>>>(whh, wt8);
    k_char_proj<<<VCC, 256, 0, stream>>>(cemb, wih, bih, bhh, cproj);
    k_lstm_block<<<NBLK, 512, 0, stream>>>(wt8, cproj, cidx, clen, pchar);
    k_sum_glove<<<dim3(5, 16), 256, 0, stream>>>(glove, widx, pglove);
    k_avg<<<4, 256, 0, stream>>>(pglove, pchar, avg);
    k_fc1<<<64, 512, 0, stream>>>(avg, fc1W, fc1b, h1g);
    k_fc2<<<1, 320, 0, stream>>>(h1g, fc2W, fc2b, out);
}